// Round 14
// baseline (4083.820 us; speedup 1.0000x reference)
//
#include <hip/hip_runtime.h>
#include <cstdint>

#define B_   8
#define N_   8192
#define M_   2048
#define CIN  64
#define COUT 128
#define FPSBLK 4          // 4 FPS blocks x 2 batches each, 512 threads

typedef unsigned long long u64;

__device__ __forceinline__ float sq3(float dx, float dy, float dz) {
    return __fadd_rn(__fadd_rn(__fmul_rn(dx, dx), __fmul_rn(dy, dy)), __fmul_rn(dz, dz));
}

// f64 DPP max step (VALU-only). Validated on gfx950 in R8.
template<int CTRL>
__device__ __forceinline__ double dppmax(double x) {
    long long b = __double_as_longlong(x);
    int lo = (int)b, hi = (int)(b >> 32);
    int plo = __builtin_amdgcn_update_dpp(lo, lo, CTRL, 0xf, 0xf, false);
    int phi = __builtin_amdgcn_update_dpp(hi, hi, CTRL, 0xf, 0xf, false);
    double p = __longlong_as_double(((long long)(unsigned)phi << 32) | (unsigned)plo);
    return fmax(x, p);
}

// ---------------- phase1: blocks 0..3 = FPS (2 batches/block, 512 thr), blocks 4..515 = GEMM ----------
// Each thread serves BOTH batches: 16 pts of A + 16 pts of B. Only dist[16]x2 (32 VGPRs) is
// register-resident; point coords are RE-LOADED from p1 every iteration (coalesced dwordx3,
// L2-resident 768KB/cloud; the in-loop __syncthreads memory barrier stops LICM from promoting
// the loads into the 128-VGPR array that the allocator demotes to scratch - R4/R9/R11-13).
// The two serial tails (DPP chain, key combine, sel fetch) are independent streams sharing ONE
// barrier -> tail amortized over 2 batches. f64-packed-key argmax (key = f64(dist)|(8191-idx))
// == exact jnp.argmax (tie -> min idx). p2 stores deferred one iteration (rotating writer wave).
__global__ __launch_bounds__(512) void phase1_kernel(const float* __restrict__ p1, float* __restrict__ p2,
                                                     const float* __restrict__ x, const float* __restrict__ W,
                                                     float* __restrict__ h) {
    __shared__ __align__(16) char smem[66560];
    int t = threadIdx.x;

    if (blockIdx.x < FPSBLK) {
        // -------- FPS, two batches per block --------
        double* wbest = (double*)smem;            // [2 bufs][2 batches][8 waves] = 32 doubles
        int lane = t & 63, wv = t >> 6;
        int b0 = blockIdx.x * 2, b1 = b0 + 1;
        const float* pA = p1 + (size_t)b0 * N_ * 3;
        const float* pB = p1 + (size_t)b1 * N_ * 3;
        float* p2A = p2 + (size_t)b0 * M_ * 3;
        float* p2B = p2 + (size_t)b1 * M_ * 3;

        float distA[16], distB[16];
#pragma unroll
        for (int j = 0; j < 16; ++j) { distA[j] = 1e10f; distB[j] = 1e10f; }

        float sxA = pA[0], syA = pA[1], szA = pA[2];
        float sxB = pB[0], syB = pB[1], szB = pB[2];

        for (int i = 1; i < M_; ++i) {
            // deferred store of selection i-1 (rotating writer wave; lanes 0/32 split A/B)
            if (wv == (i & 7)) {
                if (lane == 0)  { p2A[3*(i-1)] = sxA; p2A[3*(i-1)+1] = syA; p2A[3*(i-1)+2] = szA; }
                if (lane == 32) { p2B[3*(i-1)] = sxB; p2B[3*(i-1)+1] = syB; p2B[3*(i-1)+2] = szB; }
            }
            float bvA = -1.0f; int biA = 0;
            float bvB = -1.0f; int biB = 0;
#pragma unroll
            for (int j = 0; j < 16; ++j) {
                int idx = t + j * 512;
                const float* qa = pA + 3 * idx;
                const float* qb = pB + 3 * idx;
                float ax = qa[0], ay = qa[1], az = qa[2];
                float bx = qb[0], by = qb[1], bz = qb[2];
                float dA = sq3(__fsub_rn(ax, sxA), __fsub_rn(ay, syA), __fsub_rn(az, szA));
                float dB = sq3(__fsub_rn(bx, sxB), __fsub_rn(by, syB), __fsub_rn(bz, szB));
                float ndA = fminf(distA[j], dA);
                float ndB = fminf(distB[j], dB);
                distA[j] = ndA;
                distB[j] = ndB;
                if (ndA > bvA) { bvA = ndA; biA = idx; }   // strict >: first occurrence
                if (ndB > bvB) { bvB = ndB; biB = idx; }
            }
            // f64 keys: exact value ordering, tie -> min index
            double kA = __longlong_as_double(__double_as_longlong((double)bvA) | (u64)(8191 - biA));
            double kB = __longlong_as_double(__double_as_longlong((double)bvB) | (u64)(8191 - biB));
            kA = dppmax<0x121>(kA); kB = dppmax<0x121>(kB);   // ror:1
            kA = dppmax<0x122>(kA); kB = dppmax<0x122>(kB);   // ror:2
            kA = dppmax<0x124>(kA); kB = dppmax<0x124>(kB);   // ror:4
            kA = dppmax<0x128>(kA); kB = dppmax<0x128>(kB);   // ror:8
            kA = dppmax<0x142>(kA); kB = dppmax<0x142>(kB);   // bcast15
            kA = dppmax<0x143>(kA); kB = dppmax<0x143>(kB);   // bcast31 -> lane 63 has wave max
            int buf = (i & 1) << 4;                           // double-buffer -> 1 barrier/iter
            if (lane == 63) { wbest[buf + wv] = kA; wbest[buf + 8 + wv] = kB; }
            __syncthreads();
            const double2* WA = (const double2*)&wbest[buf];
            const double2* WB = (const double2*)&wbest[buf + 8];
            double2 a0 = WA[0], a1 = WA[1], a2 = WA[2], a3 = WA[3];
            double2 c0 = WB[0], c1 = WB[1], c2 = WB[2], c3 = WB[3];
            double mA = fmax(fmax(fmax(a0.x, a0.y), fmax(a1.x, a1.y)),
                             fmax(fmax(a2.x, a2.y), fmax(a3.x, a3.y)));
            double mB = fmax(fmax(fmax(c0.x, c0.y), fmax(c1.x, c1.y)),
                             fmax(fmax(c2.x, c2.y), fmax(c3.x, c3.y)));
            int wA = 8191 - (int)(__double_as_longlong(mA) & 0x1fff);
            int wB = 8191 - (int)(__double_as_longlong(mB) & 0x1fff);
            const float* sa = pA + 3 * wA;
            const float* sb = pB + 3 * wB;
            sxA = sa[0]; syA = sa[1]; szA = sa[2];            // L2 same-addr broadcast
            sxB = sb[0]; syB = sb[1]; szB = sb[2];
        }
        if (t == 0) { p2A[3*(M_-1)] = sxA; p2A[3*(M_-1)+1] = syA; p2A[3*(M_-1)+2] = szA; }
        if (t == 1) { p2B[3*(M_-1)] = sxB; p2B[3*(M_-1)+1] = syB; p2B[3*(M_-1)+2] = szB; }
    } else {
        // -------- GEMM: h[r][c] = dot(x[r,:64], W[c,:64]); 128-row tiles, 512 threads (R5-proven) ----
        float (*xs)[65] = (float (*)[65])smem;                 // 128x65 = 33280B
        float (*ws)[65] = (float (*)[65])(smem + 33280);       // 128x65 = 33280B
        size_t rowBase = (size_t)(blockIdx.x - FPSBLK) * 128;
        for (int idx = t; idx < COUT * CIN; idx += 512) ws[idx >> 6][idx & 63] = W[idx];
        const float* xb = x + rowBase * CIN;
        for (int idx = t; idx < 128 * CIN; idx += 512) xs[idx >> 6][idx & 63] = xb[idx];
        __syncthreads();
        int r0 = (t & 31) * 4, c0 = (t >> 5) * 8;
        float acc[4][8];
#pragma unroll
        for (int i = 0; i < 4; ++i)
#pragma unroll
            for (int j = 0; j < 8; ++j) acc[i][j] = 0.f;
        for (int k = 0; k < CIN; ++k) {
            float xv[4], wvv[8];
#pragma unroll
            for (int i = 0; i < 4; ++i) xv[i] = xs[r0 + i][k];
#pragma unroll
            for (int j = 0; j < 8; ++j) wvv[j] = ws[c0 + j][k];
#pragma unroll
            for (int i = 0; i < 4; ++i)
#pragma unroll
                for (int j = 0; j < 8; ++j) acc[i][j] = fmaf(xv[i], wvv[j], acc[i][j]);
        }
#pragma unroll
        for (int i = 0; i < 4; ++i) {
            size_t o = (rowBase + r0 + i) * COUT + c0;
            *(float4*)&h[o]     = make_float4(acc[i][0], acc[i][1], acc[i][2], acc[i][3]);
            *(float4*)&h[o + 4] = make_float4(acc[i][4], acc[i][5], acc[i][6], acc[i][7]);
        }
    }
}

// ---------------- BN stats (two-stage, deterministic) ----------------
__global__ __launch_bounds__(256) void bn_partial(const float* __restrict__ h, float* __restrict__ psum,
                                                  float* __restrict__ psq) {
    int t = threadIdx.x;
    int c = t & 127, half = t >> 7;
    size_t base = (size_t)blockIdx.x * 256;
    float s = 0.f, q = 0.f;
    for (int it = 0; it < 128; ++it) {
        float v = h[(base + it * 2 + half) * COUT + c];
        s += v; q = fmaf(v, v, q);
    }
    __shared__ float ls[256], lq[256];
    ls[t] = s; lq[t] = q;
    __syncthreads();
    if (t < 128) {
        psum[blockIdx.x * 128 + c] = ls[t] + ls[t + 128];
        psq[blockIdx.x * 128 + c]  = lq[t] + lq[t + 128];
    }
}

__global__ void bn_final(const float* __restrict__ psum, const float* __restrict__ psq,
                         const float* __restrict__ gamma, const float* __restrict__ beta,
                         float* __restrict__ bns) {
    int c = threadIdx.x;  // 128
    float s = 0.f, q = 0.f;
    for (int i = 0; i < 256; ++i) { s += psum[i * 128 + c]; q += psq[i * 128 + c]; }
    float mean = s / 65536.0f;
    float var  = q / 65536.0f - mean * mean;
    float sc = gamma[c] * rsqrtf(var + 1e-5f);
    bns[c] = sc;
    bns[128 + c] = beta[c] - mean * sc;
}

// ---------------- kNN(16) + gather + BN-affine + ReLU + maxpool, one wave per query ----------------
__global__ __launch_bounds__(256) void knn_kernel(const float* __restrict__ p1, const float* __restrict__ p2,
                                                  const float* __restrict__ h, const float* __restrict__ bns,
                                                  float* __restrict__ y) {
    int q = blockIdx.x * 4 + (threadIdx.x >> 6);
    int lane = threadIdx.x & 63;
    int b = q >> 11;             // /M_
    const float* pb = p1 + (size_t)b * N_ * 3;
    const float* pq = p2 + (size_t)q * 3;
    float qx = pq[0], qy = pq[1], qz = pq[2];
    float sqq = __fadd_rn(__fadd_rn(__fmul_rn(qx, qx), __fmul_rn(qy, qy)), __fmul_rn(qz, qz));

    float ld = 1e30f; int li = 0;   // lanes 0..15: distributed sorted top-16
    float tau = 1e30f;

    for (int c0 = 0; c0 < N_; c0 += 64) {
        int cand = c0 + lane;
        float ax = pb[3 * cand], ay = pb[3 * cand + 1], az = pb[3 * cand + 2];
        float s1 = __fadd_rn(__fadd_rn(__fmul_rn(ax, ax), __fmul_rn(ay, ay)), __fmul_rn(az, az));
        float dt = __fadd_rn(__fadd_rn(__fmul_rn(ax, qx), __fmul_rn(ay, qy)), __fmul_rn(az, qz));
        float d  = __fsub_rn(__fadd_rn(sqq, s1), __fmul_rn(2.0f, dt));   // == ref (s2+s1) - 2*dot
        unsigned long long mk = __ballot(d < tau);
        while (mk) {
            int l = __ffsll((unsigned long long)mk) - 1;
            mk &= mk - 1;
            float dd = __shfl(d, l);
            int   ii = c0 + l;
            int pos = __popcll(__ballot(ld <= dd) & 0xFFFFull);  // ties -> after existing (smaller idx kept)
            if (pos < 16) {
                float pd = __shfl_up(ld, 1);
                int   pi = __shfl_up(li, 1);
                if (lane < 16) {
                    if (lane > pos) { ld = pd; li = pi; }
                    if (lane == pos) { ld = dd; li = ii; }
                }
                tau = __shfl(ld, 15);
            }
        }
    }

    // gather 16 neighbor rows, affine+relu+max; each lane owns channels {2*lane, 2*lane+1}
    int c = lane << 1;
    float sc0 = bns[c], sc1 = bns[c + 1];
    float sh0 = bns[128 + c], sh1 = bns[128 + c + 1];
    float a0 = -1e30f, a1 = -1e30f;
#pragma unroll
    for (int t16 = 0; t16 < 16; ++t16) {
        int nb = __shfl(li, t16);
        const float* hp = h + (((size_t)(b * N_ + nb)) << 7) + c;
        float h0 = hp[0], h1 = hp[1];
        a0 = fmaxf(a0, fmaf(h0, sc0, sh0));
        a1 = fmaxf(a1, fmaf(h1, sc1, sh1));
    }
    float2 out = make_float2(fmaxf(a0, 0.f), fmaxf(a1, 0.f));
    *(float2*)&y[((size_t)q << 7) + c] = out;
}

extern "C" void kernel_launch(void* const* d_in, const int* in_sizes, int n_in,
                              void* d_out, int out_size, void* d_ws, size_t ws_size,
                              hipStream_t stream) {
    const float* x     = (const float*)d_in[0];
    const float* p1    = (const float*)d_in[1];
    const float* W     = (const float*)d_in[2];
    const float* gamma = (const float*)d_in[3];
    const float* beta  = (const float*)d_in[4];

    float* y  = (float*)d_out;
    float* p2 = y + (size_t)B_ * M_ * COUT;        // outputs concatenated: y then p2

    float* h    = (float*)d_ws;                    // 65536 x 128 f32 = 32 MB
    float* psum = h + (size_t)B_ * N_ * COUT;
    float* psq  = psum + 256 * 128;
    float* bns  = psq + 256 * 128;

    phase1_kernel<<<FPSBLK + (B_ * N_) / 128, 512, 0, stream>>>(p1, p2, x, W, h);   // FPS(2/blk) ∥ GEMM
    bn_partial<<<256, 256, 0, stream>>>(h, psum, psq);
    bn_final<<<1, 128, 0, stream>>>(psum, psq, gamma, beta, bns);
    knn_kernel<<<(B_ * M_) / 4, 256, 0, stream>>>(p1, p2, h, bns, y);
}